// Round 1
// 202.316 us; speedup vs baseline: 1.4159x; 1.4159x over previous
//
#include <hip/hip_runtime.h>

#define HH 256
#define WW 384
#define HWSZ (HH*WW)
#define NL 3
#define ANGN 7
#define A2N 49
#define NBATCH 2
#define RANKN 4
#define CN 3
#define RCN (RANKN*CN)

// padded input: each channel image is HH rows x WP cols, col index 0 <-> x = -4,
// cols [-4,-1] replicate x=0, cols [384,387] replicate x=383.
#define WP 392
#define CHS (HH*WP)                 // floats per padded channel image
#define NCH (NBATCH*NL*RCN)         // 72 channel images
#define QPR (WP/4)                  // 98 float4 quads per padded row

// ---------------- fallback: previous best kernel (used if workspace too small) ----
__global__ __launch_bounds__(256) void multilayer_kernel(
    const float* __restrict__ low_rank,
    const float* __restrict__ planes,
    float* __restrict__ out)
{
    int b = blockIdx.x;
    int pb = b % (HWSZ / 256);
    int na = b / (HWSZ / 256);
    int a  = na % A2N;
    int n  = na / A2N;

    int tid = pb * 256 + (int)threadIdx.x;
    int y = tid / WW;
    int x = tid % WW;
    float xf = (float)x, yf = (float)y;

    int lidx = a % ANGN - 3;
    int kidx = a / ANGN - 3;
    float sxa = -(float)lidx * (1.0f / WW) * 0.5f * (float)(WW - 1);
    float sya = -(float)kidx * (1.0f / HH) * 0.5f * (float)(HH - 1);

    float acc[RCN];
#pragma unroll
    for (int i = 0; i < RCN; i++) acc[i] = 1.0f;

#pragma unroll
    for (int l = 0; l < NL; l++) {
        float p = planes[n * NL + l];
        float X = fminf(fmaxf(xf + p * sxa, 0.0f), (float)(WW - 1));
        float Y = fminf(fmaxf(yf + p * sya, 0.0f), (float)(HH - 1));
        float x0f = floorf(X), y0f = floorf(Y);
        int x0 = (int)x0f, y0 = (int)y0f;
        int x1 = min(x0 + 1, WW - 1);
        int y1 = min(y0 + 1, HH - 1);
        float wx = X - x0f, wy = Y - y0f;
        float w00 = (1.0f - wx) * (1.0f - wy);
        float w01 = wx * (1.0f - wy);
        float w10 = (1.0f - wx) * wy;
        float w11 = wx * wy;

        const float* img = low_rank + (size_t)((n * NL + l) * RCN) * HWSZ;
        const float* r0 = img + y0 * WW;
        const float* r1 = img + y1 * WW;

#pragma unroll
        for (int rc = 0; rc < RCN; rc++) {
            float v00 = r0[rc * HWSZ + x0];
            float v01 = r0[rc * HWSZ + x1];
            float v10 = r1[rc * HWSZ + x0];
            float v11 = r1[rc * HWSZ + x1];
            float s = v00 * w00 + v01 * w01 + v10 * w10 + v11 * w11;
            acc[rc] *= s;
        }
    }

    int obase = ((n * A2N + a) * CN) * HWSZ + y * WW + x;
#pragma unroll
    for (int c = 0; c < CN; c++) {
        float s = acc[0 * CN + c] + acc[1 * CN + c] + acc[2 * CN + c] + acc[3 * CN + c];
        out[obase + c * HWSZ] = 0.25f * s;
    }
}

// ---------------- pre-pass: replicate-pad each channel row to WP=392 ------------
__global__ __launch_bounds__(256) void pad_kernel(const float* __restrict__ src,
                                                  float* __restrict__ dst)
{
    int idx = blockIdx.x * 256 + (int)threadIdx.x;      // quad id, exact grid
    int q   = idx % QPR;
    int row = idx / QPR;                                 // ch*HH + y
    const float* s = src + (size_t)row * WW;
    float4 v;
    if (q == 0)            { float t = s[0];      v = make_float4(t, t, t, t); }
    else if (q == QPR - 1) { float t = s[WW - 1]; v = make_float4(t, t, t, t); }
    else                   { v = *(const float4*)(s + (q - 1) * 4); }
    ((float4*)dst)[idx] = v;
}

// s[px] = h[K+px] + wx*(h[K+px+1]-h[K+px])   (compile-time K per switch case)
#define HLERP4(dst, hl, K, wxv) do {                         \
    dst[0] = hl[(K)]   + (wxv) * (hl[(K)+1] - hl[(K)]);      \
    dst[1] = hl[(K)+1] + (wxv) * (hl[(K)+2] - hl[(K)+1]);    \
    dst[2] = hl[(K)+2] + (wxv) * (hl[(K)+3] - hl[(K)+2]);    \
    dst[3] = hl[(K)+3] + (wxv) * (hl[(K)+4] - hl[(K)+3]);    \
} while (0)

// ---------------- main: 4 pixels x 7 views (all j for one k) per thread ---------
// grid = 1344 blocks = 14 (n,k) * 96 pixel-blocks; 8*168 XCD-bijective swizzle.
__global__ __launch_bounds__(256) void ml7_kernel(const float* __restrict__ padbuf,
                                                  const float* __restrict__ planes,
                                                  float* __restrict__ out)
{
    int bid = (int)blockIdx.x;
    int g   = (bid & 7) * 168 + (bid >> 3);      // contiguous pb range per XCD
    int nk  = g % (NBATCH * ANGN);
    int pb  = g / (NBATCH * ANGN);
    int k   = nk % ANGN;
    int n   = nk / ANGN;

    int g4 = pb * 256 + (int)threadIdx.x;        // pixel-group id in [0, 24576)
    int x4 = g4 % (WW / 4);
    int y  = g4 / (WW / 4);
    int xb = x4 * 4;                             // first of 4 pixels

    const float syk = -(float)(k - 3) * (0.5f * (float)(HH - 1) / (float)HH);

    float wy[NL];
    int   voff0[NL], voff1[NL];
    float wxl[NL][ANGN];
    int   i0l[NL][ANGN];

#pragma unroll
    for (int l = 0; l < NL; l++) {
        float p  = planes[n * NL + l];
        // y side: exact per-thread clamped bilinear row selection
        float Y  = fminf(fmaxf((float)y + p * syk, 0.0f), (float)(HH - 1));
        float yf = floorf(Y);
        int y0   = (int)yf;
        if (y0 > HH - 2) y0 = HH - 2;
        wy[l]    = Y - (float)y0;
        voff0[l] = y0 * WP + xb;                 // window col (xb-4) -> pad index xb
        voff1[l] = voff0[l] + WP;
        // x side: shift is uniform across pixels (x integer) -> (ox, wx) per (l,j)
#pragma unroll
        for (int j = 0; j < ANGN; j++) {
            float sxj = -(float)(j - 3) * (0.5f * (float)(WW - 1) / (float)WW);
            float dx  = p * sxj;                 // |dx| < 1.5  ->  ox in {-2..1}
            float oxf = floorf(dx);
            float wx  = dx - oxf;
            // force SGPR: keeps the switch scalar-uniform and saves VGPRs
            wxl[l][j] = __uint_as_float(__builtin_amdgcn_readfirstlane(__float_as_uint(wx)));
            i0l[l][j] = __builtin_amdgcn_readfirstlane((int)oxf + 4);  // 2..5
        }
    }

    const float* basen = padbuf + (size_t)(n * NL * RCN) * CHS;

    for (int c = 0; c < CN; c++) {
        float acc[ANGN][4];
#pragma unroll
        for (int j = 0; j < ANGN; j++) {
            acc[j][0] = 0.0f; acc[j][1] = 0.0f; acc[j][2] = 0.0f; acc[j][3] = 0.0f;
        }

        for (int r = 0; r < RANKN; r++) {
            float h[NL][12];
#pragma unroll
            for (int l = 0; l < NL; l++) {
                const float* cb = basen + (size_t)(l * RCN + r * CN + c) * CHS;
                const float* p0 = cb + voff0[l];
                const float* p1 = cb + voff1[l];
                float4 a0 = *(const float4*)(p0);
                float4 a1 = *(const float4*)(p0 + 4);
                float4 a2 = *(const float4*)(p0 + 8);
                float4 b0 = *(const float4*)(p1);
                float4 b1 = *(const float4*)(p1 + 4);
                float4 b2 = *(const float4*)(p1 + 8);
                float w = wy[l];
                // vertical lerp once, shared by all 7 j (only indices 2..9 used)
                h[l][2]  = a0.z + w * (b0.z - a0.z);
                h[l][3]  = a0.w + w * (b0.w - a0.w);
                h[l][4]  = a1.x + w * (b1.x - a1.x);
                h[l][5]  = a1.y + w * (b1.y - a1.y);
                h[l][6]  = a1.z + w * (b1.z - a1.z);
                h[l][7]  = a1.w + w * (b1.w - a1.w);
                h[l][8]  = a2.x + w * (b2.x - a2.x);
                h[l][9]  = a2.y + w * (b2.y - a2.y);
            }

#pragma unroll
            for (int j = 0; j < ANGN; j++) {
                float s[NL][4];
#pragma unroll
                for (int l = 0; l < NL; l++) {
                    float wx = wxl[l][j];
                    switch (i0l[l][j]) {         // scalar-uniform branch
                        case 2:  HLERP4(s[l], h[l], 2, wx); break;
                        case 3:  HLERP4(s[l], h[l], 3, wx); break;
                        case 4:  HLERP4(s[l], h[l], 4, wx); break;
                        default: HLERP4(s[l], h[l], 5, wx); break;
                    }
                }
#pragma unroll
                for (int px = 0; px < 4; px++)
                    acc[j][px] = fmaf(s[0][px] * s[1][px], s[2][px], acc[j][px]);
            }
        }

        size_t ob = ((size_t)((n * A2N + k * ANGN) * CN + c)) * HWSZ
                  + (size_t)y * WW + xb;
#pragma unroll
        for (int j = 0; j < ANGN; j++) {
            float4 v = make_float4(acc[j][0] * 0.25f, acc[j][1] * 0.25f,
                                   acc[j][2] * 0.25f, acc[j][3] * 0.25f);
            *(float4*)(out + ob + (size_t)(j * CN) * HWSZ) = v;
        }
    }
}

extern "C" void kernel_launch(void* const* d_in, const int* in_sizes, int n_in,
                              void* d_out, int out_size, void* d_ws, size_t ws_size,
                              hipStream_t stream) {
    const float* low_rank = (const float*)d_in[0];
    const float* planes   = (const float*)d_in[1];
    float* out = (float*)d_out;

    size_t need = (size_t)NCH * CHS * sizeof(float);   // 28,901,376 B
    if (d_ws != nullptr && ws_size >= need) {
        float* padbuf = (float*)d_ws;
        int pad_blocks = (NCH * HH * QPR) / 256;       // 7056, exact
        pad_kernel<<<pad_blocks, 256, 0, stream>>>(low_rank, padbuf);
        ml7_kernel<<<NBATCH * ANGN * (HWSZ / (4 * 256)), 256, 0, stream>>>(
            padbuf, planes, out);
    } else {
        int blocks = NBATCH * A2N * (HWSZ / 256);
        multilayer_kernel<<<blocks, 256, 0, stream>>>(low_rank, planes, out);
    }
}